// Round 1
// baseline (686.525 us; speedup 1.0000x reference)
//
#include <hip/hip_runtime.h>
#include <math.h>

#define H 2048
#define I 768
#define NE 32
#define TOPK 8
#define T 512

typedef __attribute__((ext_vector_type(4))) float f32x4;
typedef __attribute__((ext_vector_type(8))) short s16x8;

// Workspace layout (bytes)
#define WS_TOPW_OFF    1024                     // float[T*TOPK]
#define WS_ENTRIES_OFF (1024 + 16384)           // int[NE*T]
#define WS_XB_OFF      131072                   // ushort[T*H]      (2 MB)
#define WS_GLU_OFF     (4*1024*1024)            // ushort[T*TOPK*I] (6.3 MB)

__device__ __forceinline__ unsigned int f2bf(float f) {
    unsigned int u = __float_as_uint(f);
    return (u + 0x7FFFu + ((u >> 16) & 1u)) >> 16;   // RNE truncate to bf16 bits
}
__device__ __forceinline__ unsigned int cvtpk(float lo, float hi) {
    unsigned int r;
    asm("v_cvt_pk_bf16_f32 %0, %1, %2" : "=v"(r) : "v"(lo), "v"(hi));
    return r;
}

// ---------------- x f32 -> bf16 ---------------------------------------------
__global__ __launch_bounds__(256) void convert_x_kernel(
    const float* __restrict__ x, ushort* __restrict__ xb)
{
    int i = (blockIdx.x * 256 + threadIdx.x) * 8;
    float4 a = *(const float4*)(x + i);
    float4 b = *(const float4*)(x + i + 4);
    uint4 o;
    o.x = cvtpk(a.x, a.y);
    o.y = cvtpk(a.z, a.w);
    o.z = cvtpk(b.x, b.y);
    o.w = cvtpk(b.z, b.w);
    *(uint4*)(xb + i) = o;
}

// ---------------- Router ----------------------------------------------------
__global__ __launch_bounds__(256) void router_kernel(
    const float* __restrict__ x, const float* __restrict__ gw,
    float* __restrict__ topw, int* __restrict__ counts, int* __restrict__ entries)
{
    int t = blockIdx.x;
    const float* xt = x + (size_t)t * H;
    __shared__ float logits[NE];

    int e   = threadIdx.x >> 3;
    int sub = threadIdx.x & 7;
    const float* we = gw + (size_t)e * H;
    float acc = 0.f;
    for (int h = sub; h < H; h += 8) acc += xt[h] * we[h];
    acc += __shfl_down(acc, 4);
    acc += __shfl_down(acc, 2);
    acc += __shfl_down(acc, 1);
    if (sub == 0) logits[e] = acc;
    __syncthreads();

    if (threadIdx.x == 0) {
        float l[NE];
        #pragma unroll
        for (int i2 = 0; i2 < NE; ++i2) l[i2] = logits[i2];
        int bi[TOPK]; float bv[TOPK];
        for (int k = 0; k < TOPK; ++k) {
            float best = -1e30f; int b = 0;
            for (int i2 = 0; i2 < NE; ++i2)
                if (l[i2] > best) { best = l[i2]; b = i2; }
            bi[k] = b; bv[k] = best; l[b] = -1e30f;
        }
        float m = bv[0], s = 0.f, w[TOPK];
        for (int k = 0; k < TOPK; ++k) { w[k] = expf(bv[k] - m); s += w[k]; }
        float inv = 1.f / s;
        for (int k = 0; k < TOPK; ++k) {
            int p = t * TOPK + k;
            topw[p] = w[k] * inv;
            int pos = atomicAdd(&counts[bi[k]], 1);
            entries[bi[k] * T + pos] = p;
        }
    }
}

// ---------------- Gate+Up MFMA: glu[p,:] = silu(x@Wg)*(x@Wu) ----------------
// Pipelined 2-phase: raw barriers + counted vmcnt; A via global_load_lds
// (double-buffered, read-swizzled via pre-swizzled source); B reg-staged one
// tile ahead with granule-XOR-swizzled stride-72 LDS (conflict-free).
__global__ __launch_bounds__(256) void gateup_kernel(
    const ushort* __restrict__ xb, const float* __restrict__ Wg, const float* __restrict__ Wu,
    const int* __restrict__ counts, const int* __restrict__ entries,
    ushort* __restrict__ glu)
{
    int e  = blockIdx.x;
    int nt = blockIdx.y;      // 0..11
    int mt = blockIdx.z;      // 0..3
    int n  = counts[e];
    if (mt * 128 >= n) return;

    __shared__ ushort A_lds[2][128 * 64];   // unpadded, swizzle g^(r&7)
    __shared__ ushort Bg_lds[64 * 72];      // stride 72, swizzle g^((r>>3)&7)
    __shared__ ushort Bu_lds[64 * 72];
    __shared__ int prow[128];

    int tid = threadIdx.x;
    if (tid < 128) {
        int idx = mt * 128 + tid;
        prow[tid] = (idx < n) ? entries[e * T + idx] : -1;
    }
    __syncthreads();

    int lane = tid & 63;
    int wid  = tid >> 6;
    int wm = wid >> 1, wn = wid & 1;
    int quad = lane >> 4, l16 = lane & 15;

    // --- A async staging: per wave, 4 issues of 64 lanes x 16 B -> 8 rows each.
    // LDS dest is linear (base + lane*16); SOURCE is pre-swizzled so that LDS
    // slot s of row r holds chunk c = s ^ (r&7)  (rule #21).
    const ushort* asrc[4];
    #pragma unroll
    for (int j = 0; j < 4; ++j) {
        int r = (wid * 4 + j) * 8 + (lane >> 3);
        int c = (lane & 7) ^ (r & 7);
        int p = prow[r]; if (p < 0) p = 0;          // clamped: garbage rows discarded later
        asrc[j] = xb + (size_t)(p >> 3) * H + c * 8;
    }

    // --- B reg staging pointers ---
    int n4 = tid & 15, kb = tid >> 4;               // kb 0..15
    const float* pg = Wg + (size_t)e * H * I + (size_t)(kb * 2) * I + nt * 64 + n4 * 4;
    const float* pu = Wu + (size_t)e * H * I + (size_t)(kb * 2) * I + nt * 64 + n4 * 4;
    float4 bg[2][2], bu[2][2];                      // [q][row k / k+1]

    // B store offsets (ushort idx), swizzled: r*72 + ((g ^ ((r>>3)&7))<<3) + (d&3)*2
    int bofs[2][4];
    #pragma unroll
    for (int q = 0; q < 2; ++q)
        #pragma unroll
        for (int i2 = 0; i2 < 4; ++i2) {
            int r = n4 * 4 + i2, d = kb + 16 * q;
            bofs[q][i2] = r * 72 + (((d >> 2) ^ ((r >> 3) & 7)) << 3) + ((d & 3) << 1);
        }
    // fragment read offsets (swizzled)
    int aofs[2][4], brofs[2][2];
    #pragma unroll
    for (int s = 0; s < 2; ++s) {
        int g = 4 * s + quad;                        // granule of ko = s*32 + quad*8
        #pragma unroll
        for (int mi = 0; mi < 4; ++mi) {
            int R = wm * 64 + mi * 16 + l16;
            aofs[s][mi] = R * 64 + ((g ^ (R & 7)) << 3);
        }
        #pragma unroll
        for (int ni = 0; ni < 2; ++ni) {
            int R = wn * 32 + ni * 16 + l16;
            brofs[s][ni] = R * 72 + ((g ^ ((R >> 3) & 7)) << 3);
        }
    }

    f32x4 accg[4][2], accu[4][2];
    #pragma unroll
    for (int mi = 0; mi < 4; ++mi)
        #pragma unroll
        for (int ni = 0; ni < 2; ++ni) {
            #pragma unroll
            for (int r = 0; r < 4; ++r) { accg[mi][ni][r] = 0.f; accu[mi][ni][r] = 0.f; }
        }

    auto issue_a = [&](int bi2, int hc) {
        #pragma unroll
        for (int j = 0; j < 4; ++j)
            __builtin_amdgcn_global_load_lds(
                (const __attribute__((address_space(1))) void*)(asrc[j] + hc),
                (__attribute__((address_space(3))) void*)(&A_lds[bi2][(wid * 4 + j) * 512]),
                16, 0, 0);
    };
    auto load_b = [&]() {
        #pragma unroll
        for (int q = 0; q < 2; ++q) {
            const float* g0 = pg + (size_t)(32 * q) * I;
            const float* u0 = pu + (size_t)(32 * q) * I;
            bg[q][0] = *(const float4*)g0; bg[q][1] = *(const float4*)(g0 + I);
            bu[q][0] = *(const float4*)u0; bu[q][1] = *(const float4*)(u0 + I);
        }
        pg += 64 * I; pu += 64 * I;
    };
    auto store_b = [&]() {
        #pragma unroll
        for (int q = 0; q < 2; ++q) {
            const float* gl = (const float*)&bg[q][0];
            const float* gh = (const float*)&bg[q][1];
            const float* ul = (const float*)&bu[q][0];
            const float* uh = (const float*)&bu[q][1];
            #pragma unroll
            for (int i2 = 0; i2 < 4; ++i2) {
                *(unsigned int*)&Bg_lds[bofs[q][i2]] = cvtpk(gl[i2], gh[i2]);
                *(unsigned int*)&Bu_lds[bofs[q][i2]] = cvtpk(ul[i2], uh[i2]);
            }
        }
    };

    issue_a(0, 0);      // A(0) -> buf0   (before B(0) loads: in-order vmcnt covers it)
    load_b();           // B(0) regs

    for (int it = 0; it < H / 64; ++it) {
        __builtin_amdgcn_s_barrier();                     // all waves done reading LDS
        if (it + 1 < H / 64) issue_a((it + 1) & 1, (it + 1) * 64);
        store_b();                                        // implicit vmcnt wait on B(it) regs
        if (it + 1 < H / 64) load_b();                    // B(it+1) regs in flight
        // drain LDS writes; keep newest 12 loads {A(it+1),B(it+1)} in flight
        asm volatile("s_waitcnt lgkmcnt(0) vmcnt(12)" ::: "memory");
        __builtin_amdgcn_sched_barrier(0);
        __builtin_amdgcn_s_barrier();                     // publish tile it
        const ushort* Ab = A_lds[it & 1];
        #pragma unroll
        for (int s = 0; s < 2; ++s) {
            s16x8 af[4];
            #pragma unroll
            for (int mi = 0; mi < 4; ++mi) af[mi] = *(const s16x8*)&Ab[aofs[s][mi]];
            #pragma unroll
            for (int ni = 0; ni < 2; ++ni) {
                s16x8 bgf  = *(const s16x8*)&Bg_lds[brofs[s][ni]];
                s16x8 buf2 = *(const s16x8*)&Bu_lds[brofs[s][ni]];
                #pragma unroll
                for (int mi = 0; mi < 4; ++mi) {
                    accg[mi][ni] = __builtin_amdgcn_mfma_f32_16x16x32_bf16(af[mi], bgf,  accg[mi][ni], 0, 0, 0);
                    accu[mi][ni] = __builtin_amdgcn_mfma_f32_16x16x32_bf16(af[mi], buf2, accu[mi][ni], 0, 0, 0);
                }
            }
        }
    }

    // --- epilogue: silu(g)*u -> glu bf16 ---
    #pragma unroll
    for (int mi = 0; mi < 4; ++mi) {
        #pragma unroll
        for (int reg = 0; reg < 4; ++reg) {
            int r = wm * 64 + mi * 16 + quad * 4 + reg;
            int p = prow[r];
            if (p >= 0) {
                size_t base = (size_t)p * I + nt * 64 + wn * 32;
                #pragma unroll
                for (int ni = 0; ni < 2; ++ni) {
                    float g = accg[mi][ni][reg];
                    float u = accu[mi][ni][reg];
                    float sv = g / (1.f + __expf(-g)) * u;
                    glu[base + ni * 16 + l16] = (ushort)f2bf(sv);
                }
            }
        }
    }
}

// ---------------- Down MFMA: out[t,:] += topw[p] * (glu[p,:] @ Wd[e]) -------
__global__ __launch_bounds__(256) void down_kernel(
    const ushort* __restrict__ glu, const float* __restrict__ Wd,
    const int* __restrict__ counts, const int* __restrict__ entries,
    const float* __restrict__ topw, float* __restrict__ out)
{
    int e  = blockIdx.x;
    int nt = blockIdx.y;      // 0..31 over H cols
    int mt = blockIdx.z;      // 0..3
    int n  = counts[e];
    if (mt * 128 >= n) return;

    __shared__ ushort A_lds[2][128 * 64];
    __shared__ ushort Bd_lds[64 * 72];
    __shared__ int   prow[128];
    __shared__ float pw[128];

    int tid = threadIdx.x;
    if (tid < 128) {
        int idx = mt * 128 + tid;
        int p = (idx < n) ? entries[e * T + idx] : -1;
        prow[tid] = p;
        pw[tid]   = (p >= 0) ? topw[p] : 0.f;
    }
    __syncthreads();

    int lane = tid & 63;
    int wid  = tid >> 6;
    int wm = wid >> 1, wn = wid & 1;
    int quad = lane >> 4, l16 = lane & 15;

    const ushort* asrc[4];
    #pragma unroll
    for (int j = 0; j < 4; ++j) {
        int r = (wid * 4 + j) * 8 + (lane >> 3);
        int c = (lane & 7) ^ (r & 7);
        int p = prow[r]; if (p < 0) p = 0;
        asrc[j] = glu + (size_t)p * I + c * 8;
    }

    int n4 = tid & 15, kb = tid >> 4;
    const float* pd = Wd + (size_t)e * I * H + (size_t)(kb * 2) * H + nt * 64 + n4 * 4;
    float4 bd[2][2];

    int bofs[2][4];
    #pragma unroll
    for (int q = 0; q < 2; ++q)
        #pragma unroll
        for (int i2 = 0; i2 < 4; ++i2) {
            int r = n4 * 4 + i2, d = kb + 16 * q;
            bofs[q][i2] = r * 72 + (((d >> 2) ^ ((r >> 3) & 7)) << 3) + ((d & 3) << 1);
        }
    int aofs[2][4], brofs[2][2];
    #pragma unroll
    for (int s = 0; s < 2; ++s) {
        int g = 4 * s + quad;
        #pragma unroll
        for (int mi = 0; mi < 4; ++mi) {
            int R = wm * 64 + mi * 16 + l16;
            aofs[s][mi] = R * 64 + ((g ^ (R & 7)) << 3);
        }
        #pragma unroll
        for (int ni = 0; ni < 2; ++ni) {
            int R = wn * 32 + ni * 16 + l16;
            brofs[s][ni] = R * 72 + ((g ^ ((R >> 3) & 7)) << 3);
        }
    }

    f32x4 acc[4][2];
    #pragma unroll
    for (int mi = 0; mi < 4; ++mi)
        #pragma unroll
        for (int ni = 0; ni < 2; ++ni) {
            #pragma unroll
            for (int r = 0; r < 4; ++r) acc[mi][ni][r] = 0.f;
        }

    auto issue_a = [&](int bi2, int kc) {
        #pragma unroll
        for (int j = 0; j < 4; ++j)
            __builtin_amdgcn_global_load_lds(
                (const __attribute__((address_space(1))) void*)(asrc[j] + kc),
                (__attribute__((address_space(3))) void*)(&A_lds[bi2][(wid * 4 + j) * 512]),
                16, 0, 0);
    };
    auto load_b = [&]() {
        #pragma unroll
        for (int q = 0; q < 2; ++q) {
            const float* d0 = pd + (size_t)(32 * q) * H;
            bd[q][0] = *(const float4*)d0; bd[q][1] = *(const float4*)(d0 + H);
        }
        pd += 64 * H;
    };
    auto store_b = [&]() {
        #pragma unroll
        for (int q = 0; q < 2; ++q) {
            const float* dl = (const float*)&bd[q][0];
            const float* dh = (const float*)&bd[q][1];
            #pragma unroll
            for (int i2 = 0; i2 < 4; ++i2)
                *(unsigned int*)&Bd_lds[bofs[q][i2]] = cvtpk(dl[i2], dh[i2]);
        }
    };

    issue_a(0, 0);
    load_b();

    for (int it = 0; it < I / 64; ++it) {
        __builtin_amdgcn_s_barrier();
        if (it + 1 < I / 64) issue_a((it + 1) & 1, (it + 1) * 64);
        store_b();
        if (it + 1 < I / 64) load_b();
        asm volatile("s_waitcnt lgkmcnt(0) vmcnt(8)" ::: "memory");
        __builtin_amdgcn_sched_barrier(0);
        __builtin_amdgcn_s_barrier();
        const ushort* Ab = A_lds[it & 1];
        #pragma unroll
        for (int s = 0; s < 2; ++s) {
            s16x8 af[4];
            #pragma unroll
            for (int mi = 0; mi < 4; ++mi) af[mi] = *(const s16x8*)&Ab[aofs[s][mi]];
            #pragma unroll
            for (int ni = 0; ni < 2; ++ni) {
                s16x8 bf2 = *(const s16x8*)&Bd_lds[brofs[s][ni]];
                #pragma unroll
                for (int mi = 0; mi < 4; ++mi)
                    acc[mi][ni] = __builtin_amdgcn_mfma_f32_16x16x32_bf16(af[mi], bf2, acc[mi][ni], 0, 0, 0);
            }
        }
    }

    #pragma unroll
    for (int mi = 0; mi < 4; ++mi) {
        #pragma unroll
        for (int reg = 0; reg < 4; ++reg) {
            int r = wm * 64 + mi * 16 + quad * 4 + reg;
            int p = prow[r];
            if (p >= 0) {
                int tok = p >> 3;
                float wgt = pw[r];
                size_t base = (size_t)tok * H + nt * 64 + wn * 32;
                #pragma unroll
                for (int ni = 0; ni < 2; ++ni)
                    atomicAdd(&out[base + ni * 16 + l16], wgt * acc[mi][ni][reg]);
            }
        }
    }
}

extern "C" void kernel_launch(void* const* d_in, const int* in_sizes, int n_in,
                              void* d_out, int out_size, void* d_ws, size_t ws_size,
                              hipStream_t stream) {
    const float* x  = (const float*)d_in[0];
    const float* gw = (const float*)d_in[1];
    const float* Wg = (const float*)d_in[2];
    const float* Wu = (const float*)d_in[3];
    const float* Wd = (const float*)d_in[4];
    float* out = (float*)d_out;

    char* ws = (char*)d_ws;
    int*    counts  = (int*)ws;
    float*  topw    = (float*)(ws + WS_TOPW_OFF);
    int*    entries = (int*)(ws + WS_ENTRIES_OFF);
    ushort* xb      = (ushort*)(ws + WS_XB_OFF);
    ushort* glu     = (ushort*)(ws + WS_GLU_OFF);

    hipMemsetAsync(d_ws, 0, 1024, stream);                               // counts
    hipMemsetAsync(d_out, 0, (size_t)out_size * sizeof(float), stream);  // combine target

    convert_x_kernel<<<T * H / (256 * 8), 256, 0, stream>>>(x, xb);
    router_kernel<<<T, 256, 0, stream>>>(x, gw, topw, counts, entries);

    dim3 g2(NE, I / 64, 4);
    gateup_kernel<<<g2, 256, 0, stream>>>(xb, Wg, Wu, counts, entries, glu);

    dim3 g3(NE, H / 64, 4);
    down_kernel<<<g3, 256, 0, stream>>>(glu, Wd, counts, entries, topw, out);
}

// Round 2
// 674.203 us; speedup vs baseline: 1.0183x; 1.0183x over previous
//
#include <hip/hip_runtime.h>
#include <math.h>

#define H 2048
#define I 768
#define NE 32
#define TOPK 8
#define T 512

typedef __attribute__((ext_vector_type(4))) float f32x4;
typedef __attribute__((ext_vector_type(8))) short s16x8;

// Workspace layout (bytes)
#define WS_TOPW_OFF    1024                     // float[T*TOPK]
#define WS_ENTRIES_OFF (1024 + 16384)           // int[NE*T]
#define WS_XB_OFF      131072                   // ushort[T*H]      (2 MB)
#define WS_GLU_OFF     (4*1024*1024)            // ushort[T*TOPK*I] (6.3 MB)

__device__ __forceinline__ unsigned int f2bf(float f) {
    unsigned int u = __float_as_uint(f);
    return (u + 0x7FFFu + ((u >> 16) & 1u)) >> 16;   // RNE truncate to bf16 bits
}
__device__ __forceinline__ unsigned int cvtpk(float lo, float hi) {
    unsigned int r;
    asm("v_cvt_pk_bf16_f32 %0, %1, %2" : "=v"(r) : "v"(lo), "v"(hi));
    return r;
}

// ---------------- x f32 -> bf16 ---------------------------------------------
__global__ __launch_bounds__(256) void convert_x_kernel(
    const float* __restrict__ x, ushort* __restrict__ xb)
{
    int i = (blockIdx.x * 256 + threadIdx.x) * 8;
    float4 a = *(const float4*)(x + i);
    float4 b = *(const float4*)(x + i + 4);
    uint4 o;
    o.x = cvtpk(a.x, a.y);
    o.y = cvtpk(a.z, a.w);
    o.z = cvtpk(b.x, b.y);
    o.w = cvtpk(b.z, b.w);
    *(uint4*)(xb + i) = o;
}

// ---------------- Router ----------------------------------------------------
__global__ __launch_bounds__(256) void router_kernel(
    const float* __restrict__ x, const float* __restrict__ gw,
    float* __restrict__ topw, int* __restrict__ counts, int* __restrict__ entries)
{
    int t = blockIdx.x;
    const float* xt = x + (size_t)t * H;
    __shared__ float logits[NE];

    int e   = threadIdx.x >> 3;
    int sub = threadIdx.x & 7;
    const float* we = gw + (size_t)e * H;
    float acc = 0.f;
    for (int h = sub; h < H; h += 8) acc += xt[h] * we[h];
    acc += __shfl_down(acc, 4);
    acc += __shfl_down(acc, 2);
    acc += __shfl_down(acc, 1);
    if (sub == 0) logits[e] = acc;
    __syncthreads();

    if (threadIdx.x == 0) {
        float l[NE];
        #pragma unroll
        for (int i2 = 0; i2 < NE; ++i2) l[i2] = logits[i2];
        int bi[TOPK]; float bv[TOPK];
        for (int k = 0; k < TOPK; ++k) {
            float best = -1e30f; int b = 0;
            for (int i2 = 0; i2 < NE; ++i2)
                if (l[i2] > best) { best = l[i2]; b = i2; }
            bi[k] = b; bv[k] = best; l[b] = -1e30f;
        }
        float m = bv[0], s = 0.f, w[TOPK];
        for (int k = 0; k < TOPK; ++k) { w[k] = expf(bv[k] - m); s += w[k]; }
        float inv = 1.f / s;
        for (int k = 0; k < TOPK; ++k) {
            int p = t * TOPK + k;
            topw[p] = w[k] * inv;
            int pos = atomicAdd(&counts[bi[k]], 1);
            entries[bi[k] * T + pos] = p;
        }
    }
}

// ---------------- Gate+Up MFMA: glu[p,:] = silu(x@Wg)*(x@Wu) ----------------
// Grid order: x = nt (fastest) so the 12 column-tiles of ONE expert co-schedule:
// their 256B weight-row slices merge in DRAM row buffers, and they share A rows.
__global__ __launch_bounds__(256) void gateup_kernel(
    const ushort* __restrict__ xb, const float* __restrict__ Wg, const float* __restrict__ Wu,
    const int* __restrict__ counts, const int* __restrict__ entries,
    ushort* __restrict__ glu)
{
    int nt = blockIdx.x;      // 0..11  (fastest: co-scheduled within one expert)
    int e  = blockIdx.y;
    int mt = blockIdx.z;      // 0..3
    int n  = counts[e];
    if (mt * 128 >= n) return;

    __shared__ ushort A_lds[2][128 * 64];   // unpadded, swizzle g^(r&7)
    __shared__ ushort Bg_lds[64 * 72];      // stride 72, swizzle g^((r>>3)&7)
    __shared__ ushort Bu_lds[64 * 72];
    __shared__ int prow[128];

    int tid = threadIdx.x;
    if (tid < 128) {
        int idx = mt * 128 + tid;
        prow[tid] = (idx < n) ? entries[e * T + idx] : -1;
    }
    __syncthreads();

    int lane = tid & 63;
    int wid  = tid >> 6;
    int wm = wid >> 1, wn = wid & 1;
    int quad = lane >> 4, l16 = lane & 15;

    // --- A async staging: per wave, 4 issues of 64 lanes x 16 B -> 8 rows each.
    // LDS dest is linear (base + lane*16); SOURCE is pre-swizzled so that LDS
    // slot s of row r holds chunk c = s ^ (r&7)  (rule #21).
    const ushort* asrc[4];
    #pragma unroll
    for (int j = 0; j < 4; ++j) {
        int r = (wid * 4 + j) * 8 + (lane >> 3);
        int c = (lane & 7) ^ (r & 7);
        int p = prow[r]; if (p < 0) p = 0;          // clamped: garbage rows discarded later
        asrc[j] = xb + (size_t)(p >> 3) * H + c * 8;
    }

    // --- B reg staging pointers ---
    int n4 = tid & 15, kb = tid >> 4;               // kb 0..15
    const float* pg = Wg + (size_t)e * H * I + (size_t)(kb * 2) * I + nt * 64 + n4 * 4;
    const float* pu = Wu + (size_t)e * H * I + (size_t)(kb * 2) * I + nt * 64 + n4 * 4;
    float4 bg[2][2], bu[2][2];                      // [q][row k / k+1]

    // B store offsets (ushort idx), swizzled: r*72 + ((g ^ ((r>>3)&7))<<3) + (d&3)*2
    int bofs[2][4];
    #pragma unroll
    for (int q = 0; q < 2; ++q)
        #pragma unroll
        for (int i2 = 0; i2 < 4; ++i2) {
            int r = n4 * 4 + i2, d = kb + 16 * q;
            bofs[q][i2] = r * 72 + (((d >> 2) ^ ((r >> 3) & 7)) << 3) + ((d & 3) << 1);
        }
    // fragment read offsets (swizzled)
    int aofs[2][4], brofs[2][2];
    #pragma unroll
    for (int s = 0; s < 2; ++s) {
        int g = 4 * s + quad;                        // granule of ko = s*32 + quad*8
        #pragma unroll
        for (int mi = 0; mi < 4; ++mi) {
            int R = wm * 64 + mi * 16 + l16;
            aofs[s][mi] = R * 64 + ((g ^ (R & 7)) << 3);
        }
        #pragma unroll
        for (int ni = 0; ni < 2; ++ni) {
            int R = wn * 32 + ni * 16 + l16;
            brofs[s][ni] = R * 72 + ((g ^ ((R >> 3) & 7)) << 3);
        }
    }

    f32x4 accg[4][2], accu[4][2];
    #pragma unroll
    for (int mi = 0; mi < 4; ++mi)
        #pragma unroll
        for (int ni = 0; ni < 2; ++ni) {
            #pragma unroll
            for (int r = 0; r < 4; ++r) { accg[mi][ni][r] = 0.f; accu[mi][ni][r] = 0.f; }
        }

    auto issue_a = [&](int bi2, int hc) {
        #pragma unroll
        for (int j = 0; j < 4; ++j)
            __builtin_amdgcn_global_load_lds(
                (const __attribute__((address_space(1))) void*)(asrc[j] + hc),
                (__attribute__((address_space(3))) void*)(&A_lds[bi2][(wid * 4 + j) * 512]),
                16, 0, 0);
    };
    auto load_b = [&]() {
        #pragma unroll
        for (int q = 0; q < 2; ++q) {
            const float* g0 = pg + (size_t)(32 * q) * I;
            const float* u0 = pu + (size_t)(32 * q) * I;
            bg[q][0] = *(const float4*)g0; bg[q][1] = *(const float4*)(g0 + I);
            bu[q][0] = *(const float4*)u0; bu[q][1] = *(const float4*)(u0 + I);
        }
        pg += 64 * I; pu += 64 * I;
    };
    auto store_b = [&]() {
        #pragma unroll
        for (int q = 0; q < 2; ++q) {
            const float* gl = (const float*)&bg[q][0];
            const float* gh = (const float*)&bg[q][1];
            const float* ul = (const float*)&bu[q][0];
            const float* uh = (const float*)&bu[q][1];
            #pragma unroll
            for (int i2 = 0; i2 < 4; ++i2) {
                *(unsigned int*)&Bg_lds[bofs[q][i2]] = cvtpk(gl[i2], gh[i2]);
                *(unsigned int*)&Bu_lds[bofs[q][i2]] = cvtpk(ul[i2], uh[i2]);
            }
        }
    };

    issue_a(0, 0);      // A(0) -> buf0   (before B(0) loads: in-order vmcnt covers it)
    load_b();           // B(0) regs

    for (int it = 0; it < H / 64; ++it) {
        __builtin_amdgcn_s_barrier();                     // all waves done reading LDS
        if (it + 1 < H / 64) issue_a((it + 1) & 1, (it + 1) * 64);
        store_b();                                        // implicit vmcnt wait on B(it) regs
        if (it + 1 < H / 64) load_b();                    // B(it+1) regs in flight
        // drain LDS writes; keep newest 12 loads {A(it+1),B(it+1)} in flight
        asm volatile("s_waitcnt lgkmcnt(0) vmcnt(12)" ::: "memory");
        __builtin_amdgcn_sched_barrier(0);
        __builtin_amdgcn_s_barrier();                     // publish tile it
        const ushort* Ab = A_lds[it & 1];
        #pragma unroll
        for (int s = 0; s < 2; ++s) {
            s16x8 af[4];
            #pragma unroll
            for (int mi = 0; mi < 4; ++mi) af[mi] = *(const s16x8*)&Ab[aofs[s][mi]];
            #pragma unroll
            for (int ni = 0; ni < 2; ++ni) {
                s16x8 bgf  = *(const s16x8*)&Bg_lds[brofs[s][ni]];
                s16x8 buf2 = *(const s16x8*)&Bu_lds[brofs[s][ni]];
                #pragma unroll
                for (int mi = 0; mi < 4; ++mi) {
                    accg[mi][ni] = __builtin_amdgcn_mfma_f32_16x16x32_bf16(af[mi], bgf,  accg[mi][ni], 0, 0, 0);
                    accu[mi][ni] = __builtin_amdgcn_mfma_f32_16x16x32_bf16(af[mi], buf2, accu[mi][ni], 0, 0, 0);
                }
            }
        }
    }

    // --- epilogue: silu(g)*u -> glu bf16 ---
    #pragma unroll
    for (int mi = 0; mi < 4; ++mi) {
        #pragma unroll
        for (int reg = 0; reg < 4; ++reg) {
            int r = wm * 64 + mi * 16 + quad * 4 + reg;
            int p = prow[r];
            if (p >= 0) {
                size_t base = (size_t)p * I + nt * 64 + wn * 32;
                #pragma unroll
                for (int ni = 0; ni < 2; ++ni) {
                    float g = accg[mi][ni][reg];
                    float u = accu[mi][ni][reg];
                    float sv = g / (1.f + __expf(-g)) * u;
                    glu[base + ni * 16 + l16] = (ushort)f2bf(sv);
                }
            }
        }
    }
}

// ---------------- Down MFMA: out[t,:] += topw[p] * (glu[p,:] @ Wd[e]) -------
__global__ __launch_bounds__(256) void down_kernel(
    const ushort* __restrict__ glu, const float* __restrict__ Wd,
    const int* __restrict__ counts, const int* __restrict__ entries,
    const float* __restrict__ topw, float* __restrict__ out)
{
    int nt = blockIdx.x;      // 0..31 over H cols (fastest: co-scheduled per expert)
    int e  = blockIdx.y;
    int mt = blockIdx.z;      // 0..3
    int n  = counts[e];
    if (mt * 128 >= n) return;

    __shared__ ushort A_lds[2][128 * 64];
    __shared__ ushort Bd_lds[64 * 72];
    __shared__ int   prow[128];
    __shared__ float pw[128];

    int tid = threadIdx.x;
    if (tid < 128) {
        int idx = mt * 128 + tid;
        int p = (idx < n) ? entries[e * T + idx] : -1;
        prow[tid] = p;
        pw[tid]   = (p >= 0) ? topw[p] : 0.f;
    }
    __syncthreads();

    int lane = tid & 63;
    int wid  = tid >> 6;
    int wm = wid >> 1, wn = wid & 1;
    int quad = lane >> 4, l16 = lane & 15;

    const ushort* asrc[4];
    #pragma unroll
    for (int j = 0; j < 4; ++j) {
        int r = (wid * 4 + j) * 8 + (lane >> 3);
        int c = (lane & 7) ^ (r & 7);
        int p = prow[r]; if (p < 0) p = 0;
        asrc[j] = glu + (size_t)p * I + c * 8;
    }

    int n4 = tid & 15, kb = tid >> 4;
    const float* pd = Wd + (size_t)e * I * H + (size_t)(kb * 2) * H + nt * 64 + n4 * 4;
    float4 bd[2][2];

    int bofs[2][4];
    #pragma unroll
    for (int q = 0; q < 2; ++q)
        #pragma unroll
        for (int i2 = 0; i2 < 4; ++i2) {
            int r = n4 * 4 + i2, d = kb + 16 * q;
            bofs[q][i2] = r * 72 + (((d >> 2) ^ ((r >> 3) & 7)) << 3) + ((d & 3) << 1);
        }
    int aofs[2][4], brofs[2][2];
    #pragma unroll
    for (int s = 0; s < 2; ++s) {
        int g = 4 * s + quad;
        #pragma unroll
        for (int mi = 0; mi < 4; ++mi) {
            int R = wm * 64 + mi * 16 + l16;
            aofs[s][mi] = R * 64 + ((g ^ (R & 7)) << 3);
        }
        #pragma unroll
        for (int ni = 0; ni < 2; ++ni) {
            int R = wn * 32 + ni * 16 + l16;
            brofs[s][ni] = R * 72 + ((g ^ ((R >> 3) & 7)) << 3);
        }
    }

    f32x4 acc[4][2];
    #pragma unroll
    for (int mi = 0; mi < 4; ++mi)
        #pragma unroll
        for (int ni = 0; ni < 2; ++ni) {
            #pragma unroll
            for (int r = 0; r < 4; ++r) acc[mi][ni][r] = 0.f;
        }

    auto issue_a = [&](int bi2, int kc) {
        #pragma unroll
        for (int j = 0; j < 4; ++j)
            __builtin_amdgcn_global_load_lds(
                (const __attribute__((address_space(1))) void*)(asrc[j] + kc),
                (__attribute__((address_space(3))) void*)(&A_lds[bi2][(wid * 4 + j) * 512]),
                16, 0, 0);
    };
    auto load_b = [&]() {
        #pragma unroll
        for (int q = 0; q < 2; ++q) {
            const float* d0 = pd + (size_t)(32 * q) * H;
            bd[q][0] = *(const float4*)d0; bd[q][1] = *(const float4*)(d0 + H);
        }
        pd += 64 * H;
    };
    auto store_b = [&]() {
        #pragma unroll
        for (int q = 0; q < 2; ++q) {
            const float* dl = (const float*)&bd[q][0];
            const float* dh = (const float*)&bd[q][1];
            #pragma unroll
            for (int i2 = 0; i2 < 4; ++i2)
                *(unsigned int*)&Bd_lds[bofs[q][i2]] = cvtpk(dl[i2], dh[i2]);
        }
    };

    issue_a(0, 0);
    load_b();

    for (int it = 0; it < I / 64; ++it) {
        __builtin_amdgcn_s_barrier();
        if (it + 1 < I / 64) issue_a((it + 1) & 1, (it + 1) * 64);
        store_b();
        if (it + 1 < I / 64) load_b();
        asm volatile("s_waitcnt lgkmcnt(0) vmcnt(8)" ::: "memory");
        __builtin_amdgcn_sched_barrier(0);
        __builtin_amdgcn_s_barrier();
        const ushort* Ab = A_lds[it & 1];
        #pragma unroll
        for (int s = 0; s < 2; ++s) {
            s16x8 af[4];
            #pragma unroll
            for (int mi = 0; mi < 4; ++mi) af[mi] = *(const s16x8*)&Ab[aofs[s][mi]];
            #pragma unroll
            for (int ni = 0; ni < 2; ++ni) {
                s16x8 bf2 = *(const s16x8*)&Bd_lds[brofs[s][ni]];
                #pragma unroll
                for (int mi = 0; mi < 4; ++mi)
                    acc[mi][ni] = __builtin_amdgcn_mfma_f32_16x16x32_bf16(af[mi], bf2, acc[mi][ni], 0, 0, 0);
            }
        }
    }

    #pragma unroll
    for (int mi = 0; mi < 4; ++mi) {
        #pragma unroll
        for (int reg = 0; reg < 4; ++reg) {
            int r = wm * 64 + mi * 16 + quad * 4 + reg;
            int p = prow[r];
            if (p >= 0) {
                int tok = p >> 3;
                float wgt = pw[r];
                size_t base = (size_t)tok * H + nt * 64 + wn * 32;
                #pragma unroll
                for (int ni = 0; ni < 2; ++ni)
                    atomicAdd(&out[base + ni * 16 + l16], wgt * acc[mi][ni][reg]);
            }
        }
    }
}

extern "C" void kernel_launch(void* const* d_in, const int* in_sizes, int n_in,
                              void* d_out, int out_size, void* d_ws, size_t ws_size,
                              hipStream_t stream) {
    const float* x  = (const float*)d_in[0];
    const float* gw = (const float*)d_in[1];
    const float* Wg = (const float*)d_in[2];
    const float* Wu = (const float*)d_in[3];
    const float* Wd = (const float*)d_in[4];
    float* out = (float*)d_out;

    char* ws = (char*)d_ws;
    int*    counts  = (int*)ws;
    float*  topw    = (float*)(ws + WS_TOPW_OFF);
    int*    entries = (int*)(ws + WS_ENTRIES_OFF);
    ushort* xb      = (ushort*)(ws + WS_XB_OFF);
    ushort* glu     = (ushort*)(ws + WS_GLU_OFF);

    hipMemsetAsync(d_ws, 0, 1024, stream);                               // counts
    hipMemsetAsync(d_out, 0, (size_t)out_size * sizeof(float), stream);  // combine target

    convert_x_kernel<<<T * H / (256 * 8), 256, 0, stream>>>(x, xb);
    router_kernel<<<T, 256, 0, stream>>>(x, gw, topw, counts, entries);

    dim3 g2(I / 64, NE, 4);   // nt fastest -> same-expert column tiles co-schedule
    gateup_kernel<<<g2, 256, 0, stream>>>(xb, Wg, Wu, counts, entries, glu);

    dim3 g3(H / 64, NE, 4);   // nt fastest
    down_kernel<<<g3, 256, 0, stream>>>(glu, Wd, counts, entries, topw, out);
}